// Round 4
// baseline (233.638 us; speedup 1.0000x reference)
//
#include <hip/hip_runtime.h>

// GroupSort: x[32,256,64,64] fp32. For each channel pair (2k, 2k+1):
//   d = x[2k] - x[2k+1]; r = relu(d); out[2k] = x[2k] - r  (= min)
//   out[2k+1] = x[2k+1] + r  (= max)
// Pure streaming op: 128 MiB in + 128 MiB out, zero reuse within one call.
//
// Ladder:
//  R0: nt ld/st, 32B-interleaved pairs            -> kernel ~69 us
//  R1: nt ld/st, contiguous 1 KiB wave txns       -> kernel ~61 us
//  R2: plain loads + strided layout + flat grid   -> 79 us REGRESSION
//      (structure broken), BUT: FETCH_SIZE=65.5MB of 134MB -> half the
//      input stays resident in the 256MB Infinity Cache across timed
//      iterations (only the OUTPUT gets re-poisoned). True floor is
//      below the naive copy roofline.
//  R3: persistent grid (2048 blocks = 32 waves/CU) + depth-1 pipeline,
//      nt loads -> 61 us. Continuity wasn't the limiter.
//  R4 (this): R3 structure, ONE change: PLAIN cached loads (input may
//      live in LLC), keep nt stores (output must NOT evict input from
//      LLC). Expect FETCH ~65MB, kernel ~48-52 us.
//
// Layout: plane = 1024 float4. u in [0, 2^21): pair = u>>9,
// within = u&511; thread covers base+{0,512} (even) and +{1024,1536} (odd).

typedef float f32x4 __attribute__((ext_vector_type(4)));

__device__ __forceinline__ void nt_store4(f32x4* p, f32x4 v) {
    __builtin_nontemporal_store(v, p);
}

__device__ __forceinline__ void pair_op(const f32x4 a, const f32x4 b,
                                        f32x4& lo, f32x4& hi) {
#pragma unroll
    for (int i = 0; i < 4; ++i) {
        float d = a[i] - b[i];
        float r = d > 0.0f ? d : 0.0f;
        lo[i] = a[i] - r;
        hi[i] = b[i] + r;
    }
}

__device__ __forceinline__ long base_of(long u) {
    const long pair   = u >> 9;
    const long within = u & 511;
    return pair * 2048 + within;
}

#define NTHREADS_TOTAL (2048L * 256L)   // 524288; 32 waves/CU resident
#define NITER 4                         // 524288 * 4 = 2^21 work units

__global__ __launch_bounds__(256, 8) void groupsort_kernel(
    const f32x4* __restrict__ x, f32x4* __restrict__ out) {
    const long t = (long)blockIdx.x * blockDim.x + threadIdx.x;

    long u = t;
    long base = base_of(u);
    f32x4 a0 = x[base];
    f32x4 a1 = x[base + 512];
    f32x4 b0 = x[base + 1024];
    f32x4 b1 = x[base + 1536];

#pragma unroll
    for (int it = 0; it < NITER; ++it) {
        long nbase = 0;
        f32x4 na0, na1, nb0, nb1;
        if (it < NITER - 1) {               // compile-time after unroll
            nbase = base_of(u + NTHREADS_TOTAL);
            na0 = x[nbase];
            na1 = x[nbase + 512];
            nb0 = x[nbase + 1024];
            nb1 = x[nbase + 1536];
        }

        f32x4 lo0, hi0, lo1, hi1;
        pair_op(a0, b0, lo0, hi0);
        pair_op(a1, b1, lo1, hi1);
        nt_store4(out + base,        lo0);
        nt_store4(out + base + 512,  lo1);
        nt_store4(out + base + 1024, hi0);
        nt_store4(out + base + 1536, hi1);

        if (it < NITER - 1) {
            base = nbase;
            a0 = na0; a1 = na1; b0 = nb0; b1 = nb1;
            u += NTHREADS_TOTAL;
        }
    }
}

extern "C" void kernel_launch(void* const* d_in, const int* in_sizes, int n_in,
                              void* d_out, int out_size, void* d_ws, size_t ws_size,
                              hipStream_t stream) {
    const f32x4* x = (const f32x4*)d_in[0];
    f32x4* out = (f32x4*)d_out;
    const int threads = 256;
    const int blocks = 2048;   // 8 blocks/CU x 4 waves = 32 waves/CU resident
    groupsort_kernel<<<blocks, threads, 0, stream>>>(x, out);
}

// Round 5
// 223.782 us; speedup vs baseline: 1.0440x; 1.0440x over previous
//
#include <hip/hip_runtime.h>

// GroupSort: x[32,256,64,64] fp32. For each channel pair (2k, 2k+1):
//   d = x[2k] - x[2k+1]; r = relu(d); out[2k] = x[2k] - r  (= min)
//   out[2k+1] = x[2k+1] + r  (= max)
// Pure streaming op: 128 MiB in + 128 MiB out, zero reuse within one call.
//
// Ladder (kernel-dispatch time; dur_us = kernel + ~156 us harness fills):
//  R0: nt ld/st, 32B-interleaved pairs        -> ~69 us
//  R1: nt ld/st, contiguous 1 KiB wave txns   -> ~62 us
//  R2: plain ld + nt st, strided, flat grid   -> ~80 us  REGRESSION
//  R3: nt ld/st, persistent grid + pipeline   -> ~66 us  (continuity not
//      the limiter; structure kept)
//  R4: plain ld + nt st on R3 structure       -> ~83 us  REGRESSION
//      => plain cached loads cost 15-20 us vs nt loads on a touch-once
//      stream (L2 allocate-path overhead > HBM-byte savings). CONFIRMED 2x.
//  R5 (this): nt loads + PLAIN stores. Both high-BW references (fill
//      kernel 6.7 TB/s, m13 copy 6.29 TB/s) use plain stores: L2
//      write-combines and schedules full-burst writebacks, decoupling
//      store retirement from DRAM write timing. nt stores stream past L2
//      per-request and serialize against the read stream. One variable.
//
// Layout: plane = 1024 float4. u in [0, 2^21): pair = u>>9,
// within = u&511; thread covers base+{0,512} (even) and +{1024,1536} (odd).

typedef float f32x4 __attribute__((ext_vector_type(4)));

__device__ __forceinline__ f32x4 nt_load4(const f32x4* p) {
    return __builtin_nontemporal_load(p);
}

__device__ __forceinline__ void pair_op(const f32x4 a, const f32x4 b,
                                        f32x4& lo, f32x4& hi) {
#pragma unroll
    for (int i = 0; i < 4; ++i) {
        float d = a[i] - b[i];
        float r = d > 0.0f ? d : 0.0f;
        lo[i] = a[i] - r;
        hi[i] = b[i] + r;
    }
}

__device__ __forceinline__ long base_of(long u) {
    const long pair   = u >> 9;
    const long within = u & 511;
    return pair * 2048 + within;
}

#define NTHREADS_TOTAL (2048L * 256L)   // 524288; 32 waves/CU resident
#define NITER 4                         // 524288 * 4 = 2^21 work units

__global__ __launch_bounds__(256, 8) void groupsort_kernel(
    const f32x4* __restrict__ x, f32x4* __restrict__ out) {
    const long t = (long)blockIdx.x * blockDim.x + threadIdx.x;

    long u = t;
    long base = base_of(u);
    f32x4 a0 = nt_load4(x + base);
    f32x4 a1 = nt_load4(x + base + 512);
    f32x4 b0 = nt_load4(x + base + 1024);
    f32x4 b1 = nt_load4(x + base + 1536);

#pragma unroll
    for (int it = 0; it < NITER; ++it) {
        long nbase = 0;
        f32x4 na0, na1, nb0, nb1;
        if (it < NITER - 1) {               // compile-time after unroll
            nbase = base_of(u + NTHREADS_TOTAL);
            na0 = nt_load4(x + nbase);
            na1 = nt_load4(x + nbase + 512);
            nb0 = nt_load4(x + nbase + 1024);
            nb1 = nt_load4(x + nbase + 1536);
        }

        f32x4 lo0, hi0, lo1, hi1;
        pair_op(a0, b0, lo0, hi0);
        pair_op(a1, b1, lo1, hi1);
        out[base]        = lo0;   // PLAIN stores: L2 write-combine path
        out[base + 512]  = lo1;
        out[base + 1024] = hi0;
        out[base + 1536] = hi1;

        if (it < NITER - 1) {
            base = nbase;
            a0 = na0; a1 = na1; b0 = nb0; b1 = nb1;
            u += NTHREADS_TOTAL;
        }
    }
}

extern "C" void kernel_launch(void* const* d_in, const int* in_sizes, int n_in,
                              void* d_out, int out_size, void* d_ws, size_t ws_size,
                              hipStream_t stream) {
    const f32x4* x = (const f32x4*)d_in[0];
    f32x4* out = (f32x4*)d_out;
    const int threads = 256;
    const int blocks = 2048;   // 8 blocks/CU x 4 waves = 32 waves/CU resident
    groupsort_kernel<<<blocks, threads, 0, stream>>>(x, out);
}